// Round 1
// baseline (9998.438 us; speedup 1.0000x reference)
//
#include <hip/hip_runtime.h>
#include <hip/hip_fp16.h>

// CascadedAttention: B=32, T=1024, D=1024, O=256. All I/O f32.
// ws (33.55 MB): E[b][t][o]=exp(2*(in@Ua+Ba2)) bf16; IC[b][t][o]=in@Co bf16.
// UoHp staged in d_out (f32), read at step t before the step's publish,
// overwritten by pred only after the step-t exchange completes.
// R8: scan now 128 blocks x 1024 thr; b=blk&31, g=blk>>5 (4 groups/b, each
// owns a 256-t' slice). Exchange shrunk 8->4 groups (1032 words), publishes/
// polls use plain agent-scope atomic store/load (no RMW), own slice filled
// locally (poll only 774 foreign words), phase C k-loop staggered by oq to
// kill the 4-way LDS bank conflict on smF/smVa float4 reads.
// Tag protocol unchanged: every word is (t<<16 | f16), parity dbuf on t&1.

typedef unsigned int uint32;
typedef unsigned short u16;

#define NTH 1024

__device__ __forceinline__ float b2f(u16 u) { return __uint_as_float(((uint32)u) << 16); }
__device__ __forceinline__ u16 f2b(float f) {
    uint32 u = __float_as_uint(f);
    uint32 r = u + 0x7fffu + ((u >> 16) & 1u);
    return (u16)(r >> 16);
}
__device__ __forceinline__ float lo_bf(uint32 d) { return __uint_as_float(d << 16); }
__device__ __forceinline__ float hi_bf(uint32 d) { return __uint_as_float(d & 0xffff0000u); }
__device__ __forceinline__ float tanh_fast(float x) {
    float e = __expf(x + x);
    return 1.0f - 2.0f * __builtin_amdgcn_rcpf(e + 1.0f);
}
__device__ __forceinline__ uint32 packh(float f, int t) {
    return (((uint32)t) << 16) | (uint32)__half_as_ushort(__float2half(f));
}
__device__ __forceinline__ float unpackh(uint32 w) {
    return __half2float(__ushort_as_half((unsigned short)(w & 0xFFFFu)));
}
// must match unpackh(packh(x,t)) exactly (bitwise-identical pred across blocks)
__device__ __forceinline__ float hround(float x) { return __half2float(__float2half(x)); }

__device__ __forceinline__ uint32 poll_ld(uint32* p) {
    return __hip_atomic_load(p, __ATOMIC_RELAXED, __HIP_MEMORY_SCOPE_AGENT);
}
__device__ __forceinline__ void pub_st(uint32* p, uint32 v) {
    __hip_atomic_store(p, v, __ATOMIC_RELAXED, __HIP_MEMORY_SCOPE_AGENT);
}

#define OFF_E  ((size_t)0)
#define OFF_IC ((size_t)16777216)
#define WS_NEEDED ((size_t)33554432)

// exchange: [parity][b][g*258 + k], k<256 = P_g[o], 256 = m_g, 257 = S_g
// 4 groups -> 1032 words per (parity,b)
__device__ uint32 g_P[2][32][1032];
__device__ float g_embWo[256];

__global__ __launch_bounds__(256) void init_k() {
    int i = blockIdx.x * 256 + threadIdx.x;       // grid 258 -> 66048 exact
    ((uint32*)g_P)[i] = 0xFFFF0000u;
}

__global__ void setup_embWo(const float* __restrict__ emb, const float* __restrict__ Wo) {
    int o = threadIdx.x;
    float a = 0.f;
    for (int j = 0; j < 256; j++) a = fmaf(emb[o * 256 + j], Wo[j], a);
    g_embWo[o] = a;
}

// ---------------- K1: fused precompute GEMM (f32 in) ----------------
__global__ __launch_bounds__(256) void gemm_pre(
    const float* __restrict__ in, const float* __restrict__ Ua,
    const float* __restrict__ Uo, const float* __restrict__ Co,
    const float* __restrict__ Ba2, const float* __restrict__ Bo2,
    const float* __restrict__ Bo3, const float* __restrict__ Bo4,
    u16* __restrict__ E, float* __restrict__ outStage, u16* __restrict__ ic) {
    __shared__ __align__(16) float smA[32][132];
    __shared__ __align__(16) float smB[32][128];

    int tid = threadIdx.x;
    int rt = blockIdx.x, ct = blockIdx.y;
    int mat = ct >> 1;
    int o0 = (ct & 1) * 128;
    const float* W = (mat == 0) ? Ua : (mat == 1 ? Uo : Co);
    int r0 = rt * 128;
    int b = r0 >> 10, t0 = r0 & 1023;
    int tr = tid >> 4, tc = tid & 15;

    float acc[8][8];
#pragma unroll
    for (int i = 0; i < 8; i++)
#pragma unroll
        for (int j = 0; j < 8; j++) acc[i][j] = 0.f;

    for (int kc = 0; kc < 1024; kc += 32) {
#pragma unroll
        for (int l = 0; l < 4; l++) {
            int s = tid + l * 256;
            int i = s >> 3, c = s & 7;
            float4 v = *(const float4*)(in + (size_t)(r0 + i) * 1024 + kc + c * 4);
            smA[c * 4 + 0][i] = v.x;
            smA[c * 4 + 1][i] = v.y;
            smA[c * 4 + 2][i] = v.z;
            smA[c * 4 + 3][i] = v.w;
        }
#pragma unroll
        for (int l = 0; l < 4; l++) {
            int s = tid + l * 256;
            int dd = s >> 5, c = s & 31;
            *(float4*)&smB[dd][c * 4] = *(const float4*)(W + (size_t)(kc + dd) * 256 + o0 + c * 4);
        }
        __syncthreads();
#pragma unroll 4
        for (int j = 0; j < 32; j++) {
            float a0[8], b0[8];
            *(float4*)&a0[0] = *(const float4*)&smA[j][tr * 8];
            *(float4*)&a0[4] = *(const float4*)&smA[j][tr * 8 + 4];
            *(float4*)&b0[0] = *(const float4*)&smB[j][tc * 8];
            *(float4*)&b0[4] = *(const float4*)&smB[j][tc * 8 + 4];
#pragma unroll
            for (int rr = 0; rr < 8; rr++)
#pragma unroll
                for (int cc = 0; cc < 8; cc++) acc[rr][cc] = fmaf(a0[rr], b0[cc], acc[rr][cc]);
        }
        __syncthreads();
    }

    if (mat == 0) {
#pragma unroll
        for (int rr = 0; rr < 8; rr++) {
            int t = t0 + tr * 8 + rr;
#pragma unroll
            for (int cc = 0; cc < 8; cc++) {
                int o = o0 + tc * 8 + cc;
                float v = __expf(2.f * (acc[rr][cc] + Ba2[t * 256 + o]));
                E[((((size_t)b << 10) + t) << 8) + o] = f2b(v);   // [b][t][o]
            }
        }
    } else if (mat == 1) {
#pragma unroll
        for (int rr = 0; rr < 8; rr++) {
            int t = t0 + tr * 8 + rr;
            int t1 = (t + 1) & 1023;
#pragma unroll
            for (int cc = 0; cc < 8; cc++) {
                int o = o0 + tc * 8 + cc;
                outStage[(((size_t)b << 10) + t1) * 256 + o] = acc[rr][cc] + Bo2[o] + Bo3[o] + Bo4[o];
            }
        }
    } else {
#pragma unroll
        for (int rr = 0; rr < 8; rr++) {
            int t = t0 + tr * 8 + rr;
#pragma unroll
            for (int cc = 0; cc < 8; cc++)
                ic[(((size_t)b << 10) + t) * 256 + o0 + tc * 8 + cc] = f2b(acc[rr][cc]);
        }
    }
}

// ---------------- K2: scan, 4 blocks/b x 1024 thr, single exchange/step -----
__global__ __launch_bounds__(NTH) void seq4(
    const float* __restrict__ Wa, const float* __restrict__ Va,
    const float* __restrict__ Ba1, const float* __restrict__ Ba3,
    const u16* __restrict__ E, const u16* __restrict__ IC,
    float* __restrict__ out) {
    __shared__ uint32 smWa2[128 * 256];                 // 128 KB bf16-packed Wa
    __shared__ __align__(16) float smScratch[4096];     // 16 KB (GEMV / P / poll)
    __shared__ float smPred[256], smQ[256], smF[256], smVa[256], smBa1[256];
    __shared__ float smS[256], smEe[256], smBa3[256];
    __shared__ float smT[16];

    int tid = threadIdx.x;
    int b = blockIdx.x & 31, g = blockIdx.x >> 5;       // g in 0..3
    int lane = tid & 63, w = tid >> 6;                  // 16 waves
    int t0 = g << 8;                                    // 256-t' slice

    if (tid < 256) {
        smVa[tid] = Va[tid]; smBa1[tid] = Ba1[tid];
        smPred[tid] = 0.f; smQ[tid] = 0.f;
        smBa3[tid] = Ba3[t0 + tid];
    }
    for (int idx = tid; idx < 32768; idx += NTH) {
        int j2 = idx >> 8, o = idx & 255;
        uint32 u0 = (uint32)f2b(Wa[(size_t)(2 * j2) * 256 + o]);
        uint32 u1 = (uint32)f2b(Wa[(size_t)(2 * j2 + 1) * 256 + o]);
        smWa2[idx] = u0 | (u1 << 16);
    }
    __syncthreads();

    float sv = (tid < 256) ? smVa[tid] : 0.f;
#pragma unroll
    for (int off = 32; off; off >>= 1) sv += __shfl_xor(sv, off, 64);
    if (lane == 0) smT[w] = sv;
    __syncthreads();
    float sumVa = smT[0] + smT[1] + smT[2] + smT[3];
    float myEmb = (tid < 256) ? g_embWo[tid] : 0.f;
    __syncthreads();

    const u16* Eb = E + ((size_t)b << 18);
    const u16* ICb = IC + ((size_t)b << 18);
    float* outb = out + ((size_t)b << 18);
    long bud = 100000000L;   // hang guard (bounded: produces wrong result, not timeout)

    int base = g * 258;

    for (int t = 0; t < 1024; t++) {
        uint32* buf = &g_P[t & 1][b][0];
        // UoHp row read — precedes publish (ordering: read -> our publish ->
        // others' poll-pass -> others' write of this row)
        float uoh = (tid < 256) ? outb[((size_t)t << 8) + tid] : 0.f;

        // ---- phase A partials (tid<256) + WaS GEMV (all 1024) ----
        float pv = 0.f;
        if (tid < 256) {
            pv = smPred[tid];
            float m = pv;
#pragma unroll
            for (int off = 32; off; off >>= 1) m = fmaxf(m, __shfl_xor(m, off, 64));
            if (lane == 0) smT[w] = m;
        }
        {
            int o = tid & 255, h = tid >> 8;            // h in 0..3, 32 j2 each
            const uint32* wp = &smWa2[(h << 5) * 256 + o];
            const float* qp = &smQ[h << 6];
            float a = 0.f;
#pragma unroll 8
            for (int j2 = 0; j2 < 32; j2++) {
                float2 q2 = *(const float2*)&qp[j2 * 2];
                uint32 p = wp[j2 << 8];
                a = fmaf(lo_bf(p), q2.x, a);
                a = fmaf(hi_bf(p), q2.y, a);
            }
            smScratch[tid] = a;
        }
        __syncthreads();   // S1
        if (tid < 256) {
            float M = fmaxf(fmaxf(smT[0], smT[1]), fmaxf(smT[2], smT[3]));
            float e = __expf(pv - M);
            float s1 = e, s2 = e * myEmb;
#pragma unroll
            for (int off = 32; off; off >>= 1) {
                s1 += __shfl_xor(s1, off, 64);
                s2 += __shfl_xor(s2, off, 64);
            }
            if (lane == 0) { smT[4 + w] = s1; smT[8 + w] = s2; }
            smF[tid] = __expf(2.f * (smBa1[tid] + smScratch[tid] + smScratch[256 + tid] +
                                     smScratch[512 + tid] + smScratch[768 + tid]));
        }
        __syncthreads();   // S2
        float p_val = (smT[8] + smT[9] + smT[10] + smT[11]) *
                      __builtin_amdgcn_rcpf(smT[4] + smT[5] + smT[6] + smT[7]);

        // ---- phase C: scores for own 256-t' slice, 4 thr/row ----
        // k staggered by oq so the 4 concurrent smF/smVa float4 addresses
        // land in 4 distinct bank quadrants (kills 4-way ds_read_b128 conflict)
        {
            int tl = tid >> 2, oq = tid & 3;
            const uint4* row = (const uint4*)(Eb + (((size_t)(t0 + tl)) << 8) + (oq << 6));
            float acc = 0.f;
#pragma unroll
            for (int k = 0; k < 8; k++) {
                int kk = (k + oq) & 7;
                uint4 ev = row[kk];
                int ob = (oq << 6) + (kk << 3);
                float4 fA = *(const float4*)&smF[ob];
                float4 fB = *(const float4*)&smF[ob + 4];
                float4 vA = *(const float4*)&smVa[ob];
                float4 vB = *(const float4*)&smVa[ob + 4];
                acc = fmaf(vA.x, __builtin_amdgcn_rcpf(fmaf(lo_bf(ev.x), fA.x, 1.f)), acc);
                acc = fmaf(vA.y, __builtin_amdgcn_rcpf(fmaf(hi_bf(ev.x), fA.y, 1.f)), acc);
                acc = fmaf(vA.z, __builtin_amdgcn_rcpf(fmaf(lo_bf(ev.y), fA.z, 1.f)), acc);
                acc = fmaf(vA.w, __builtin_amdgcn_rcpf(fmaf(hi_bf(ev.y), fA.w, 1.f)), acc);
                acc = fmaf(vB.x, __builtin_amdgcn_rcpf(fmaf(lo_bf(ev.z), fB.x, 1.f)), acc);
                acc = fmaf(vB.y, __builtin_amdgcn_rcpf(fmaf(hi_bf(ev.z), fB.y, 1.f)), acc);
                acc = fmaf(vB.z, __builtin_amdgcn_rcpf(fmaf(lo_bf(ev.w), fB.z, 1.f)), acc);
                acc = fmaf(vB.w, __builtin_amdgcn_rcpf(fmaf(hi_bf(ev.w), fB.w, 1.f)), acc);
            }
            acc += __shfl_xor(acc, 1, 64);
            acc += __shfl_xor(acc, 2, 64);
            if (oq == 0) smS[tl] = sumVa - 2.f * acc + smBa3[tl];
        }
        __syncthreads();   // S3
        // ---- local softmax stats over 256 scores ----
        float m_g, S_g;
        if (tid < 256) {
            float s = smS[tid];
            float mm = s;
#pragma unroll
            for (int off = 32; off; off >>= 1) mm = fmaxf(mm, __shfl_xor(mm, off, 64));
            if (lane == 0) smT[w] = mm;
        }
        __syncthreads();   // S4
        if (tid < 256) {
            float mg = fmaxf(fmaxf(smT[0], smT[1]), fmaxf(smT[2], smT[3]));
            float e = __expf(smS[tid] - mg);
            smEe[tid] = e;
            float ls = e;
#pragma unroll
            for (int off = 32; off; off >>= 1) ls += __shfl_xor(ls, off, 64);
            if (lane == 0) smT[4 + w] = ls;
        }
        __syncthreads();   // S5
        m_g = fmaxf(fmaxf(smT[0], smT[1]), fmaxf(smT[2], smT[3]));
        S_g = smT[4] + smT[5] + smT[6] + smT[7];
        // publish m,S early — lets the stats words travel during P staging
        if (tid == 0) {
            pub_st(&buf[base + 256], packh(m_g, t));
            pub_st(&buf[base + 257], packh(S_g, t));
        }

        // ---- P_g partial: e-weighted IC rows of own slice (16 rowgroups) ----
        {
            int rg = tid >> 6, oc = tid & 63, o4 = oc << 2;
            const u16* icp = ICb + (((size_t)t0) << 8) + o4;
            float4 a4 = {0.f, 0.f, 0.f, 0.f};
#pragma unroll 4
            for (int r = 0; r < 16; r++) {
                int row = (rg << 4) + r;
                float e = smEe[row];
                uint2 iv = *(const uint2*)(icp + ((size_t)row << 8));
                a4.x = fmaf(e, lo_bf(iv.x), a4.x);
                a4.y = fmaf(e, hi_bf(iv.x), a4.y);
                a4.z = fmaf(e, lo_bf(iv.y), a4.z);
                a4.w = fmaf(e, hi_bf(iv.y), a4.w);
            }
            *(float4*)&smScratch[rg * 256 + o4] = a4;
        }
        __syncthreads();   // S6
        // ---- publish P (plain agent-scope stores, tag-validated) ----
        float Pmine = 0.f;
        if (tid < 256) {
#pragma unroll
            for (int rg = 0; rg < 16; rg++) Pmine += smScratch[rg * 256 + tid];
            pub_st(&buf[base + tid], packh(Pmine, t));
        }
        __syncthreads();   // S7 (smScratch reads done before poll overwrites)
        // ---- own-fill + poll 774 foreign words ----
        {
            uint32 tt = (uint32)t;
            // fill own slice locally with the SAME half-rounded values others
            // will unpack -> all 4 blocks stay bitwise-identical
            if (tid < 256) smScratch[base + tid] = hround(Pmine);
            if (tid == 0) {
                smScratch[base + 256] = hround(m_g);
                smScratch[base + 257] = hround(S_g);
            }
            bool own0 = ((uint32)(tid - base) < 258u);
            bool p1 = (tid < 8) && (g != 3);            // words 1024..1031 are g3's
            uint32 w0 = own0 ? (tt << 16) : 0xFFFF0000u;
            uint32 w1 = p1 ? 0xFFFF0000u : (tt << 16);
            while (bud > 0) {
                if ((w0 >> 16) != tt) w0 = poll_ld(&buf[tid]);
                if ((w1 >> 16) != tt) w1 = poll_ld(&buf[1024 + tid]);
                if (((w0 >> 16) == tt) & ((w1 >> 16) == tt)) break;
                bud--;
            }
            if (!own0) smScratch[tid] = unpackh(w0);
            if (p1) smScratch[1024 + tid] = unpackh(w1);
        }
        __syncthreads();   // S8
        // ---- merge + full pred rebuild (tid<256) ----
        if (tid < 256) {
            float M = smScratch[256];
#pragma unroll
            for (int g2 = 1; g2 < 4; g2++) M = fmaxf(M, smScratch[g2 * 258 + 256]);
            float L = 0.f, Pt = 0.f;
#pragma unroll
            for (int g2 = 0; g2 < 4; g2++) {
                float eg = __expf(smScratch[g2 * 258 + 256] - M);
                L = fmaf(eg, smScratch[g2 * 258 + 257], L);
                Pt = fmaf(eg, smScratch[g2 * 258 + tid], Pt);
            }
            float pr = p_val + uoh + Pt * __builtin_amdgcn_rcpf(L);
            if ((tid >> 6) == g) outb[((size_t)t << 8) + tid] = pr;
            smPred[tid] = pr;
            smQ[tid] = tanh_fast(pr);
        }
        __syncthreads();   // S9
    }
}

// ---------------- fallback (ws too small): diagnostic zero-fill ----------------
__global__ void zero_k(uint32* out, int n) {
    int i = blockIdx.x * 1024 + threadIdx.x;
    if (i < n) out[i] = 0;
}

extern "C" void kernel_launch(void* const* d_in, const int* in_sizes, int n_in,
                              void* d_out, int out_size, void* d_ws, size_t ws_size,
                              hipStream_t stream) {
    const float* in = (const float*)d_in[0];
    const float* Wa = (const float*)d_in[1];
    const float* Ua = (const float*)d_in[2];
    const float* Va = (const float*)d_in[3];
    const float* Ba1 = (const float*)d_in[4];
    const float* Ba2 = (const float*)d_in[5];
    const float* Ba3 = (const float*)d_in[6];
    const float* Wo = (const float*)d_in[7];
    const float* Uo = (const float*)d_in[8];
    const float* Co = (const float*)d_in[9];
    const float* Bo2 = (const float*)d_in[10];
    const float* Bo3 = (const float*)d_in[11];
    const float* Bo4 = (const float*)d_in[12];
    const float* emb = (const float*)d_in[13];
    float* out = (float*)d_out;
    char* ws = (char*)d_ws;

    if (ws_size < WS_NEEDED) {
        zero_k<<<(out_size + 1023) / 1024, 1024, 0, stream>>>((uint32*)out, out_size);
        return;
    }

    u16* E = (u16*)(ws + OFF_E);
    u16* icp = (u16*)(ws + OFF_IC);

    init_k<<<258, 256, 0, stream>>>();
    setup_embWo<<<1, 256, 0, stream>>>(emb, Wo);
    gemm_pre<<<dim3(256, 6), 256, 0, stream>>>(in, Ua, Uo, Co, Ba2, Bo2, Bo3, Bo4, E, out, icp);
    seq4<<<128, NTH, 0, stream>>>(Wa, Va, Ba1, Ba3, E, icp, out);
}

// Round 2
// 7333.204 us; speedup vs baseline: 1.3634x; 1.3634x over previous
//
#include <hip/hip_runtime.h>
#include <hip/hip_fp16.h>

// CascadedAttention: B=32, T=1024, D=1024, O=256. All I/O f32.
// ws (33.55 MB): E[b][t][o]=exp(2*(in@Ua+Ba2)) bf16; IC[b][t][o]=in@Co bf16.
// UoHp staged in d_out (f32), read at step t before the step's publish,
// overwritten by pred only after the step-t exchange completes.
// Scan: 256 blocks x 512 thr; b=blk&31, g=blk>>5. ONE exchange per step:
// block g publishes (m_g, S_g, P_g[256]) of its 128-t' slice as
// (t<<16|f16) tagged words (atomicExch); all blocks poll tags (atomicAdd+0),
// merge online-softmax style, and rebuild the FULL pred locally.
// R9 (revert R8's reshape+relaxed-atomics; keep proven pieces):
//  - phase C k-loop staggered by oq (kills 4-way LDS conflict; PMC-proven
//    8.05e8 -> 0 in R8)
//  - own 258 words filled locally with identical hround values (skip one
//    MALL round trip on the critical path); poll only 1806 foreign words
//  - m_g,S_g published right after S5 (travel during P staging)
// R7 fix retained: poll caches init to tag 0xFFFF for foreign words.

typedef unsigned int uint32;
typedef unsigned short u16;

#define NTH 512

__device__ __forceinline__ float b2f(u16 u) { return __uint_as_float(((uint32)u) << 16); }
__device__ __forceinline__ u16 f2b(float f) {
    uint32 u = __float_as_uint(f);
    uint32 r = u + 0x7fffu + ((u >> 16) & 1u);
    return (u16)(r >> 16);
}
__device__ __forceinline__ float lo_bf(uint32 d) { return __uint_as_float(d << 16); }
__device__ __forceinline__ float hi_bf(uint32 d) { return __uint_as_float(d & 0xffff0000u); }
__device__ __forceinline__ float tanh_fast(float x) {
    float e = __expf(x + x);
    return 1.0f - 2.0f * __builtin_amdgcn_rcpf(e + 1.0f);
}
__device__ __forceinline__ uint32 packh(float f, int t) {
    return (((uint32)t) << 16) | (uint32)__half_as_ushort(__float2half(f));
}
__device__ __forceinline__ float unpackh(uint32 w) {
    return __half2float(__ushort_as_half((unsigned short)(w & 0xFFFFu)));
}
// must match unpackh(packh(x,t)) exactly (bitwise-identical pred across blocks)
__device__ __forceinline__ float hround(float x) { return __half2float(__float2half(x)); }

#define OFF_E  ((size_t)0)
#define OFF_IC ((size_t)16777216)
#define WS_NEEDED ((size_t)33554432)

// exchange: [parity][b][g*258 + k], k<256 = P_g[o], 256 = m_g, 257 = S_g
__device__ uint32 g_P[2][32][2064];
__device__ float g_embWo[256];

__global__ __launch_bounds__(256) void init_k() {
    int i = blockIdx.x * 256 + threadIdx.x;       // grid 516 -> 132096
    ((uint32*)g_P)[i] = 0xFFFF0000u;
}

__global__ void setup_embWo(const float* __restrict__ emb, const float* __restrict__ Wo) {
    int o = threadIdx.x;
    float a = 0.f;
    for (int j = 0; j < 256; j++) a = fmaf(emb[o * 256 + j], Wo[j], a);
    g_embWo[o] = a;
}

// ---------------- K1: fused precompute GEMM (f32 in) ----------------
__global__ __launch_bounds__(256) void gemm_pre(
    const float* __restrict__ in, const float* __restrict__ Ua,
    const float* __restrict__ Uo, const float* __restrict__ Co,
    const float* __restrict__ Ba2, const float* __restrict__ Bo2,
    const float* __restrict__ Bo3, const float* __restrict__ Bo4,
    u16* __restrict__ E, float* __restrict__ outStage, u16* __restrict__ ic) {
    __shared__ __align__(16) float smA[32][132];
    __shared__ __align__(16) float smB[32][128];

    int tid = threadIdx.x;
    int rt = blockIdx.x, ct = blockIdx.y;
    int mat = ct >> 1;
    int o0 = (ct & 1) * 128;
    const float* W = (mat == 0) ? Ua : (mat == 1 ? Uo : Co);
    int r0 = rt * 128;
    int b = r0 >> 10, t0 = r0 & 1023;
    int tr = tid >> 4, tc = tid & 15;

    float acc[8][8];
#pragma unroll
    for (int i = 0; i < 8; i++)
#pragma unroll
        for (int j = 0; j < 8; j++) acc[i][j] = 0.f;

    for (int kc = 0; kc < 1024; kc += 32) {
#pragma unroll
        for (int l = 0; l < 4; l++) {
            int s = tid + l * 256;
            int i = s >> 3, c = s & 7;
            float4 v = *(const float4*)(in + (size_t)(r0 + i) * 1024 + kc + c * 4);
            smA[c * 4 + 0][i] = v.x;
            smA[c * 4 + 1][i] = v.y;
            smA[c * 4 + 2][i] = v.z;
            smA[c * 4 + 3][i] = v.w;
        }
#pragma unroll
        for (int l = 0; l < 4; l++) {
            int s = tid + l * 256;
            int dd = s >> 5, c = s & 31;
            *(float4*)&smB[dd][c * 4] = *(const float4*)(W + (size_t)(kc + dd) * 256 + o0 + c * 4);
        }
        __syncthreads();
#pragma unroll 4
        for (int j = 0; j < 32; j++) {
            float a0[8], b0[8];
            *(float4*)&a0[0] = *(const float4*)&smA[j][tr * 8];
            *(float4*)&a0[4] = *(const float4*)&smA[j][tr * 8 + 4];
            *(float4*)&b0[0] = *(const float4*)&smB[j][tc * 8];
            *(float4*)&b0[4] = *(const float4*)&smB[j][tc * 8 + 4];
#pragma unroll
            for (int rr = 0; rr < 8; rr++)
#pragma unroll
                for (int cc = 0; cc < 8; cc++) acc[rr][cc] = fmaf(a0[rr], b0[cc], acc[rr][cc]);
        }
        __syncthreads();
    }

    if (mat == 0) {
#pragma unroll
        for (int rr = 0; rr < 8; rr++) {
            int t = t0 + tr * 8 + rr;
#pragma unroll
            for (int cc = 0; cc < 8; cc++) {
                int o = o0 + tc * 8 + cc;
                float v = __expf(2.f * (acc[rr][cc] + Ba2[t * 256 + o]));
                E[((((size_t)b << 10) + t) << 8) + o] = f2b(v);   // [b][t][o]
            }
        }
    } else if (mat == 1) {
#pragma unroll
        for (int rr = 0; rr < 8; rr++) {
            int t = t0 + tr * 8 + rr;
            int t1 = (t + 1) & 1023;
#pragma unroll
            for (int cc = 0; cc < 8; cc++) {
                int o = o0 + tc * 8 + cc;
                outStage[(((size_t)b << 10) + t1) * 256 + o] = acc[rr][cc] + Bo2[o] + Bo3[o] + Bo4[o];
            }
        }
    } else {
#pragma unroll
        for (int rr = 0; rr < 8; rr++) {
            int t = t0 + tr * 8 + rr;
#pragma unroll
            for (int cc = 0; cc < 8; cc++)
                ic[(((size_t)b << 10) + t) * 256 + o0 + tc * 8 + cc] = f2b(acc[rr][cc]);
        }
    }
}

// ---------------- K2: scan, 8 blocks/b x 512 thr, single exchange/step --------
__global__ __launch_bounds__(NTH) void seq8(
    const float* __restrict__ Wa, const float* __restrict__ Va,
    const float* __restrict__ Ba1, const float* __restrict__ Ba3,
    const u16* __restrict__ E, const u16* __restrict__ IC,
    float* __restrict__ out) {
    __shared__ uint32 smWa2[128 * 256];     // 128 KB bf16-packed Wa
    __shared__ __align__(16) float smScratch[2064];
    __shared__ float smPred[256], smQ[256], smF[256], smVa[256], smBa1[256];
    __shared__ float smS[128], smEe[128], smBa3[128];
    __shared__ float smT[16];

    int tid = threadIdx.x;
    int b = blockIdx.x & 31, g = blockIdx.x >> 5;
    int lane = tid & 63, w = tid >> 6;
    int t0 = g << 7;
    int base = g * 258;

    if (tid < 256) {
        smVa[tid] = Va[tid]; smBa1[tid] = Ba1[tid];
        smPred[tid] = 0.f; smQ[tid] = 0.f;
    }
    if (tid < 128) smBa3[tid] = Ba3[t0 + tid];
    for (int idx = tid; idx < 32768; idx += NTH) {
        int j2 = idx >> 8, o = idx & 255;
        uint32 u0 = (uint32)f2b(Wa[(size_t)(2 * j2) * 256 + o]);
        uint32 u1 = (uint32)f2b(Wa[(size_t)(2 * j2 + 1) * 256 + o]);
        smWa2[idx] = u0 | (u1 << 16);
    }
    __syncthreads();

    float sv = (tid < 256) ? smVa[tid] : 0.f;
#pragma unroll
    for (int off = 32; off; off >>= 1) sv += __shfl_xor(sv, off, 64);
    if (lane == 0) smT[w] = sv;
    __syncthreads();
    float sumVa = smT[0] + smT[1] + smT[2] + smT[3];
    float myEmb = (tid < 256) ? g_embWo[tid] : 0.f;
    __syncthreads();

    const u16* Eb = E + ((size_t)b << 18);
    const u16* ICb = IC + ((size_t)b << 18);
    float* outb = out + ((size_t)b << 18);
    long bud = 1000000000L;   // hang guard

    // foreign/own word classification for the 4(+1) poll slots (t-invariant)
    bool own0 = ((uint32)(tid        - base) < 258u);
    bool own1 = ((uint32)(tid + 512  - base) < 258u);
    bool own2 = ((uint32)(tid + 1024 - base) < 258u);
    bool own3 = ((uint32)(tid + 1536 - base) < 258u);
    bool has4 = (tid < 16) && (g != 7);     // words 2048..2063 belong to g7

    for (int t = 0; t < 1024; t++) {
        uint32* buf = &g_P[t & 1][b][0];
        // UoHp row read — precedes publish (ordering: read -> our publish ->
        // others' poll-pass -> others' write of this row)
        float uoh = (tid < 256) ? outb[((size_t)t << 8) + tid] : 0.f;

        // ---- phase A partials (tid<256) + WaS GEMV (all 512) ----
        float pv = 0.f;
        if (tid < 256) {
            pv = smPred[tid];
            float m = pv;
#pragma unroll
            for (int off = 32; off; off >>= 1) m = fmaxf(m, __shfl_xor(m, off, 64));
            if (lane == 0) smT[w] = m;
        }
        {
            int o = tid & 255, h = tid >> 8;
            const uint32* wp = &smWa2[(h << 6) * 256 + o];
            const float* qp = &smQ[h << 7];
            float a = 0.f;
#pragma unroll 8
            for (int j2 = 0; j2 < 64; j2++) {
                float2 q2 = *(const float2*)&qp[j2 * 2];
                uint32 p = wp[j2 << 8];
                a = fmaf(lo_bf(p), q2.x, a);
                a = fmaf(hi_bf(p), q2.y, a);
            }
            smScratch[tid] = a;
        }
        __syncthreads();   // S1
        if (tid < 256) {
            float M = fmaxf(fmaxf(smT[0], smT[1]), fmaxf(smT[2], smT[3]));
            float e = __expf(pv - M);
            float s1 = e, s2 = e * myEmb;
#pragma unroll
            for (int off = 32; off; off >>= 1) {
                s1 += __shfl_xor(s1, off, 64);
                s2 += __shfl_xor(s2, off, 64);
            }
            if (lane == 0) { smT[4 + w] = s1; smT[8 + w] = s2; }
            smF[tid] = __expf(2.f * (smBa1[tid] + smScratch[tid] + smScratch[256 + tid]));
        }
        __syncthreads();   // S2
        float p_val = (smT[8] + smT[9] + smT[10] + smT[11]) *
                      __builtin_amdgcn_rcpf(smT[4] + smT[5] + smT[6] + smT[7]);

        // ---- phase C: scores for own 128-t' slice, 4 thr/row ----
        // k staggered by oq so the 4 concurrent smF/smVa float4 addresses land
        // in 4 distinct bank quadrants (R8 PMC: conflicts 8.05e8 -> 0)
        {
            int tl = tid >> 2, oq = tid & 3;
            const uint4* row = (const uint4*)(Eb + (((size_t)(t0 + tl)) << 8) + (oq << 6));
            float acc = 0.f;
#pragma unroll
            for (int k = 0; k < 8; k++) {
                int kk = (k + oq) & 7;
                uint4 ev = row[kk];
                int ob = (oq << 6) + (kk << 3);
                float4 fA = *(const float4*)&smF[ob];
                float4 fB = *(const float4*)&smF[ob + 4];
                float4 vA = *(const float4*)&smVa[ob];
                float4 vB = *(const float4*)&smVa[ob + 4];
                acc = fmaf(vA.x, __builtin_amdgcn_rcpf(fmaf(lo_bf(ev.x), fA.x, 1.f)), acc);
                acc = fmaf(vA.y, __builtin_amdgcn_rcpf(fmaf(hi_bf(ev.x), fA.y, 1.f)), acc);
                acc = fmaf(vA.z, __builtin_amdgcn_rcpf(fmaf(lo_bf(ev.y), fA.z, 1.f)), acc);
                acc = fmaf(vA.w, __builtin_amdgcn_rcpf(fmaf(hi_bf(ev.y), fA.w, 1.f)), acc);
                acc = fmaf(vB.x, __builtin_amdgcn_rcpf(fmaf(lo_bf(ev.z), fB.x, 1.f)), acc);
                acc = fmaf(vB.y, __builtin_amdgcn_rcpf(fmaf(hi_bf(ev.z), fB.y, 1.f)), acc);
                acc = fmaf(vB.z, __builtin_amdgcn_rcpf(fmaf(lo_bf(ev.w), fB.z, 1.f)), acc);
                acc = fmaf(vB.w, __builtin_amdgcn_rcpf(fmaf(hi_bf(ev.w), fB.w, 1.f)), acc);
            }
            acc += __shfl_xor(acc, 1, 64);
            acc += __shfl_xor(acc, 2, 64);
            if (oq == 0) smS[tl] = sumVa - 2.f * acc + smBa3[tl];
        }
        __syncthreads();   // S3
        // ---- local softmax stats over 128 scores ----
        float m_g = 0.f, S_g = 0.f;
        if (tid < 128) {
            float s = smS[tid];
            float mm = s;
#pragma unroll
            for (int off = 32; off; off >>= 1) mm = fmaxf(mm, __shfl_xor(mm, off, 64));
            if (lane == 0) smT[w] = mm;
        }
        __syncthreads();   // S4
        if (tid < 128) {
            m_g = fmaxf(smT[0], smT[1]);
            float e = __expf(smS[tid] - m_g);
            smEe[tid] = e;
            float ls = e;
#pragma unroll
            for (int off = 32; off; off >>= 1) ls += __shfl_xor(ls, off, 64);
            if (lane == 0) smT[2 + w] = ls;
        }
        __syncthreads();   // S5
        m_g = fmaxf(smT[0], smT[1]);
        S_g = smT[2] + smT[3];
        // early publish: m,S travel while we stage P
        if (tid == 0) {
            atomicExch(&buf[base + 256], packh(m_g, t));
            atomicExch(&buf[base + 257], packh(S_g, t));
        }

        // ---- P_g partial: e-weighted IC rows of own slice ----
        {
            int rg = tid >> 6, oc = tid & 63, o4 = oc << 2;
            const u16* icp = ICb + (((size_t)t0) << 8) + o4;
            float4 a4 = {0.f, 0.f, 0.f, 0.f};
#pragma unroll 4
            for (int r = 0; r < 16; r++) {
                int row = (rg << 4) + r;
                float e = smEe[row];
                uint2 iv = *(const uint2*)(icp + ((size_t)row << 8));
                a4.x = fmaf(e, lo_bf(iv.x), a4.x);
                a4.y = fmaf(e, hi_bf(iv.x), a4.y);
                a4.z = fmaf(e, lo_bf(iv.y), a4.z);
                a4.w = fmaf(e, hi_bf(iv.y), a4.w);
            }
            *(float4*)&smScratch[rg * 256 + o4] = a4;
        }
        __syncthreads();   // S6
        // ---- publish P (own 256 words) ----
        float Pmine = 0.f;
        if (tid < 256) {
#pragma unroll
            for (int rg = 0; rg < 8; rg++) Pmine += smScratch[rg * 256 + tid];
            atomicExch(&buf[base + tid], packh(Pmine, t));
        }
        __syncthreads();   // S7 (smScratch reads done before poll overwrites)
        // ---- own-fill + poll 1806 foreign words, overlapped RTs ----
        {
            uint32 tt = (uint32)t;
            // fill own slice locally with the SAME half-rounded values others
            // will unpack -> all 8 blocks stay bitwise-identical; removes the
            // round trip of waiting for our OWN stores to come back from MALL
            if (tid < 256) smScratch[base + tid] = hround(Pmine);
            if (tid == 0) {
                smScratch[base + 256] = hround(m_g);
                smScratch[base + 257] = hround(S_g);
            }
            uint32 w0 = own0 ? (tt << 16) : 0xFFFF0000u;
            uint32 w1 = own1 ? (tt << 16) : 0xFFFF0000u;
            uint32 w2 = own2 ? (tt << 16) : 0xFFFF0000u;
            uint32 w3 = own3 ? (tt << 16) : 0xFFFF0000u;
            uint32 w4 = has4 ? 0xFFFF0000u : (tt << 16);
            while (bud > 0) {
                if ((w0 >> 16) != tt) w0 = atomicAdd(&buf[tid], 0u);
                if ((w1 >> 16) != tt) w1 = atomicAdd(&buf[tid + 512], 0u);
                if ((w2 >> 16) != tt) w2 = atomicAdd(&buf[tid + 1024], 0u);
                if ((w3 >> 16) != tt) w3 = atomicAdd(&buf[tid + 1536], 0u);
                if (has4 && (w4 >> 16) != tt) w4 = atomicAdd(&buf[tid + 2048], 0u);
                if ((w0 >> 16) == tt && (w1 >> 16) == tt && (w2 >> 16) == tt &&
                    (w3 >> 16) == tt && (w4 >> 16) == tt) break;
                bud--;
            }
            if (!own0) smScratch[tid] = unpackh(w0);
            if (!own1) smScratch[tid + 512] = unpackh(w1);
            if (!own2) smScratch[tid + 1024] = unpackh(w2);
            if (!own3) smScratch[tid + 1536] = unpackh(w3);
            if (has4) smScratch[tid + 2048] = unpackh(w4);
        }
        __syncthreads();   // S8
        // ---- merge + full pred rebuild (tid<256) ----
        if (tid < 256) {
            float M = smScratch[256];
#pragma unroll
            for (int g2 = 1; g2 < 8; g2++) M = fmaxf(M, smScratch[g2 * 258 + 256]);
            float L = 0.f, Pt = 0.f;
#pragma unroll
            for (int g2 = 0; g2 < 8; g2++) {
                float eg = __expf(smScratch[g2 * 258 + 256] - M);
                L = fmaf(eg, smScratch[g2 * 258 + 257], L);
                Pt = fmaf(eg, smScratch[g2 * 258 + tid], Pt);
            }
            float pr = p_val + uoh + Pt * __builtin_amdgcn_rcpf(L);
            if ((tid >> 5) == g) outb[((size_t)t << 8) + tid] = pr;
            smPred[tid] = pr;
            smQ[tid] = tanh_fast(pr);
        }
        __syncthreads();   // S9
    }
}

// ---------------- fallback (ws too small): diagnostic zero-fill ----------------
__global__ void zero_k(uint32* out, int n) {
    int i = blockIdx.x * 1024 + threadIdx.x;
    if (i < n) out[i] = 0;
}

extern "C" void kernel_launch(void* const* d_in, const int* in_sizes, int n_in,
                              void* d_out, int out_size, void* d_ws, size_t ws_size,
                              hipStream_t stream) {
    const float* in = (const float*)d_in[0];
    const float* Wa = (const float*)d_in[1];
    const float* Ua = (const float*)d_in[2];
    const float* Va = (const float*)d_in[3];
    const float* Ba1 = (const float*)d_in[4];
    const float* Ba2 = (const float*)d_in[5];
    const float* Ba3 = (const float*)d_in[6];
    const float* Wo = (const float*)d_in[7];
    const float* Uo = (const float*)d_in[8];
    const float* Co = (const float*)d_in[9];
    const float* Bo2 = (const float*)d_in[10];
    const float* Bo3 = (const float*)d_in[11];
    const float* Bo4 = (const float*)d_in[12];
    const float* emb = (const float*)d_in[13];
    float* out = (float*)d_out;
    char* ws = (char*)d_ws;

    if (ws_size < WS_NEEDED) {
        zero_k<<<(out_size + 1023) / 1024, 1024, 0, stream>>>((uint32*)out, out_size);
        return;
    }

    u16* E = (u16*)(ws + OFF_E);
    u16* icp = (u16*)(ws + OFF_IC);

    init_k<<<516, 256, 0, stream>>>();
    setup_embWo<<<1, 256, 0, stream>>>(emb, Wo);
    gemm_pre<<<dim3(256, 6), 256, 0, stream>>>(in, Ua, Uo, Co, Ba2, Bo2, Bo3, Bo4, E, out, icp);
    seq8<<<256, NTH, 0, stream>>>(Wa, Va, Ba1, Ba3, E, icp, out);
}

// Round 3
// 6947.869 us; speedup vs baseline: 1.4391x; 1.0555x over previous
//
#include <hip/hip_runtime.h>
#include <hip/hip_fp16.h>

// CascadedAttention: B=32, T=1024, D=1024, O=256. All I/O f32.
// ws (33.55 MB): E[b][t][o]=exp(2*(in@Ua+Ba2)) bf16; IC[b][t][o]=in@Co bf16.
// UoHp staged in d_out (f32), read at step t before the step's publish,
// overwritten by pred only after the step-t exchange completes.
// Scan: 256 blocks x 512 thr; b=blk&31, g=blk>>5.
// R10: flag-based exchange replaces per-word tagged polling.
//  - publish P[256],m,S as f32 relaxed agent-scope stores (g_Pf)
//  - __syncthreads() drains vmcnt (release), then thread0 stores flag=t
//  - pollers spin on 7 foreign FLAG words only (atomicAdd+0 RMW, proven fast)
//  - after flags: ONE batch of 8 strided P loads/thread + 16 mS loads,
//    relaxed agent-scope (R8-proven visibility), no retries, no pack/unpack
//  - all blocks merge identical published f32 -> bitwise-identical preds
// Ordering safety: A's t+2 overwrite of g_Pf[t&1] is issued only after A saw
// every block's t+1 flag, which each block stores only after its t-merge
// loads completed (vmcnt-drained before its t+1 publish barrier).
// Retained: phase-C oq-stagger (PMC-proven conflicts 0), early m,S publish.

typedef unsigned int uint32;
typedef unsigned short u16;

#define NTH 512

__device__ __forceinline__ float b2f(u16 u) { return __uint_as_float(((uint32)u) << 16); }
__device__ __forceinline__ u16 f2b(float f) {
    uint32 u = __float_as_uint(f);
    uint32 r = u + 0x7fffu + ((u >> 16) & 1u);
    return (u16)(r >> 16);
}
__device__ __forceinline__ float lo_bf(uint32 d) { return __uint_as_float(d << 16); }
__device__ __forceinline__ float hi_bf(uint32 d) { return __uint_as_float(d & 0xffff0000u); }
__device__ __forceinline__ float tanh_fast(float x) {
    float e = __expf(x + x);
    return 1.0f - 2.0f * __builtin_amdgcn_rcpf(e + 1.0f);
}

__device__ __forceinline__ uint32 coh_ld(const uint32* p) {
    return __hip_atomic_load(p, __ATOMIC_RELAXED, __HIP_MEMORY_SCOPE_AGENT);
}
__device__ __forceinline__ void coh_st(uint32* p, uint32 v) {
    __hip_atomic_store(p, v, __ATOMIC_RELAXED, __HIP_MEMORY_SCOPE_AGENT);
}

#define OFF_E  ((size_t)0)
#define OFF_IC ((size_t)16777216)
#define WS_NEEDED ((size_t)33554432)

// exchange: per (parity,b,g): P f32-bits [0..255], m at 256, S at 257 (264 stride)
__device__ uint32 g_Pf[2][32][8][264];
__device__ uint32 g_flag[2][32][8];     // flag word = t when group g's data is ready
__device__ float g_embWo[256];

__global__ __launch_bounds__(512) void init_flags() {
    ((uint32*)g_flag)[threadIdx.x] = 0xFFFFFFFFu;    // 2*32*8 = 512 words
}

__global__ void setup_embWo(const float* __restrict__ emb, const float* __restrict__ Wo) {
    int o = threadIdx.x;
    float a = 0.f;
    for (int j = 0; j < 256; j++) a = fmaf(emb[o * 256 + j], Wo[j], a);
    g_embWo[o] = a;
}

// ---------------- K1: fused precompute GEMM (f32 in) ----------------
__global__ __launch_bounds__(256) void gemm_pre(
    const float* __restrict__ in, const float* __restrict__ Ua,
    const float* __restrict__ Uo, const float* __restrict__ Co,
    const float* __restrict__ Ba2, const float* __restrict__ Bo2,
    const float* __restrict__ Bo3, const float* __restrict__ Bo4,
    u16* __restrict__ E, float* __restrict__ outStage, u16* __restrict__ ic) {
    __shared__ __align__(16) float smA[32][132];
    __shared__ __align__(16) float smB[32][128];

    int tid = threadIdx.x;
    int rt = blockIdx.x, ct = blockIdx.y;
    int mat = ct >> 1;
    int o0 = (ct & 1) * 128;
    const float* W = (mat == 0) ? Ua : (mat == 1 ? Uo : Co);
    int r0 = rt * 128;
    int b = r0 >> 10, t0 = r0 & 1023;
    int tr = tid >> 4, tc = tid & 15;

    float acc[8][8];
#pragma unroll
    for (int i = 0; i < 8; i++)
#pragma unroll
        for (int j = 0; j < 8; j++) acc[i][j] = 0.f;

    for (int kc = 0; kc < 1024; kc += 32) {
#pragma unroll
        for (int l = 0; l < 4; l++) {
            int s = tid + l * 256;
            int i = s >> 3, c = s & 7;
            float4 v = *(const float4*)(in + (size_t)(r0 + i) * 1024 + kc + c * 4);
            smA[c * 4 + 0][i] = v.x;
            smA[c * 4 + 1][i] = v.y;
            smA[c * 4 + 2][i] = v.z;
            smA[c * 4 + 3][i] = v.w;
        }
#pragma unroll
        for (int l = 0; l < 4; l++) {
            int s = tid + l * 256;
            int dd = s >> 5, c = s & 31;
            *(float4*)&smB[dd][c * 4] = *(const float4*)(W + (size_t)(kc + dd) * 256 + o0 + c * 4);
        }
        __syncthreads();
#pragma unroll 4
        for (int j = 0; j < 32; j++) {
            float a0[8], b0[8];
            *(float4*)&a0[0] = *(const float4*)&smA[j][tr * 8];
            *(float4*)&a0[4] = *(const float4*)&smA[j][tr * 8 + 4];
            *(float4*)&b0[0] = *(const float4*)&smB[j][tc * 8];
            *(float4*)&b0[4] = *(const float4*)&smB[j][tc * 8 + 4];
#pragma unroll
            for (int rr = 0; rr < 8; rr++)
#pragma unroll
                for (int cc = 0; cc < 8; cc++) acc[rr][cc] = fmaf(a0[rr], b0[cc], acc[rr][cc]);
        }
        __syncthreads();
    }

    if (mat == 0) {
#pragma unroll
        for (int rr = 0; rr < 8; rr++) {
            int t = t0 + tr * 8 + rr;
#pragma unroll
            for (int cc = 0; cc < 8; cc++) {
                int o = o0 + tc * 8 + cc;
                float v = __expf(2.f * (acc[rr][cc] + Ba2[t * 256 + o]));
                E[((((size_t)b << 10) + t) << 8) + o] = f2b(v);   // [b][t][o]
            }
        }
    } else if (mat == 1) {
#pragma unroll
        for (int rr = 0; rr < 8; rr++) {
            int t = t0 + tr * 8 + rr;
            int t1 = (t + 1) & 1023;
#pragma unroll
            for (int cc = 0; cc < 8; cc++) {
                int o = o0 + tc * 8 + cc;
                outStage[(((size_t)b << 10) + t1) * 256 + o] = acc[rr][cc] + Bo2[o] + Bo3[o] + Bo4[o];
            }
        }
    } else {
#pragma unroll
        for (int rr = 0; rr < 8; rr++) {
            int t = t0 + tr * 8 + rr;
#pragma unroll
            for (int cc = 0; cc < 8; cc++)
                ic[(((size_t)b << 10) + t) * 256 + o0 + tc * 8 + cc] = f2b(acc[rr][cc]);
        }
    }
}

// ---------------- K2: scan, 8 blocks/b x 512 thr, flag exchange/step --------
__global__ __launch_bounds__(NTH) void seq8(
    const float* __restrict__ Wa, const float* __restrict__ Va,
    const float* __restrict__ Ba1, const float* __restrict__ Ba3,
    const u16* __restrict__ E, const u16* __restrict__ IC,
    float* __restrict__ out) {
    __shared__ uint32 smWa2[128 * 256];     // 128 KB bf16-packed Wa
    __shared__ __align__(16) float smScratch[2064];
    __shared__ float smPred[256], smQ[256], smF[256], smVa[256], smBa1[256];
    __shared__ float smS[128], smEe[128], smBa3[128];
    __shared__ float smT[16];

    int tid = threadIdx.x;
    int b = blockIdx.x & 31, g = blockIdx.x >> 5;
    int lane = tid & 63, w = tid >> 6;
    int t0 = g << 7;

    if (tid < 256) {
        smVa[tid] = Va[tid]; smBa1[tid] = Ba1[tid];
        smPred[tid] = 0.f; smQ[tid] = 0.f;
    }
    if (tid < 128) smBa3[tid] = Ba3[t0 + tid];
    for (int idx = tid; idx < 32768; idx += NTH) {
        int j2 = idx >> 8, o = idx & 255;
        uint32 u0 = (uint32)f2b(Wa[(size_t)(2 * j2) * 256 + o]);
        uint32 u1 = (uint32)f2b(Wa[(size_t)(2 * j2 + 1) * 256 + o]);
        smWa2[idx] = u0 | (u1 << 16);
    }
    __syncthreads();

    float sv = (tid < 256) ? smVa[tid] : 0.f;
#pragma unroll
    for (int off = 32; off; off >>= 1) sv += __shfl_xor(sv, off, 64);
    if (lane == 0) smT[w] = sv;
    __syncthreads();
    float sumVa = smT[0] + smT[1] + smT[2] + smT[3];
    float myEmb = (tid < 256) ? g_embWo[tid] : 0.f;
    __syncthreads();

    const u16* Eb = E + ((size_t)b << 18);
    const u16* ICb = IC + ((size_t)b << 18);
    float* outb = out + ((size_t)b << 18);
    long bud = 1000000000L;   // hang guard (bounded: wrong result, not timeout)

    for (int t = 0; t < 1024; t++) {
        uint32* bufP  = &g_Pf[t & 1][b][g][0];
        uint32* flags = &g_flag[t & 1][b][0];
        // UoHp row read — precedes publish (ordering: read -> our publish ->
        // others' flag-pass -> others' write of this row)
        float uoh = (tid < 256) ? outb[((size_t)t << 8) + tid] : 0.f;

        // ---- phase A partials (tid<256) + WaS GEMV (all 512) ----
        float pv = 0.f;
        if (tid < 256) {
            pv = smPred[tid];
            float m = pv;
#pragma unroll
            for (int off = 32; off; off >>= 1) m = fmaxf(m, __shfl_xor(m, off, 64));
            if (lane == 0) smT[w] = m;
        }
        {
            int o = tid & 255, h = tid >> 8;
            const uint32* wp = &smWa2[(h << 6) * 256 + o];
            const float* qp = &smQ[h << 7];
            float a = 0.f;
#pragma unroll 8
            for (int j2 = 0; j2 < 64; j2++) {
                float2 q2 = *(const float2*)&qp[j2 * 2];
                uint32 p = wp[j2 << 8];
                a = fmaf(lo_bf(p), q2.x, a);
                a = fmaf(hi_bf(p), q2.y, a);
            }
            smScratch[tid] = a;
        }
        __syncthreads();   // S1
        if (tid < 256) {
            float M = fmaxf(fmaxf(smT[0], smT[1]), fmaxf(smT[2], smT[3]));
            float e = __expf(pv - M);
            float s1 = e, s2 = e * myEmb;
#pragma unroll
            for (int off = 32; off; off >>= 1) {
                s1 += __shfl_xor(s1, off, 64);
                s2 += __shfl_xor(s2, off, 64);
            }
            if (lane == 0) { smT[4 + w] = s1; smT[8 + w] = s2; }
            smF[tid] = __expf(2.f * (smBa1[tid] + smScratch[tid] + smScratch[256 + tid]));
        }
        __syncthreads();   // S2
        float p_val = (smT[8] + smT[9] + smT[10] + smT[11]) *
                      __builtin_amdgcn_rcpf(smT[4] + smT[5] + smT[6] + smT[7]);

        // ---- phase C: scores for own 128-t' slice, 4 thr/row ----
        // k staggered by oq (R8 PMC: LDS conflicts 8.05e8 -> 0)
        {
            int tl = tid >> 2, oq = tid & 3;
            const uint4* row = (const uint4*)(Eb + (((size_t)(t0 + tl)) << 8) + (oq << 6));
            float acc = 0.f;
#pragma unroll
            for (int k = 0; k < 8; k++) {
                int kk = (k + oq) & 7;
                uint4 ev = row[kk];
                int ob = (oq << 6) + (kk << 3);
                float4 fA = *(const float4*)&smF[ob];
                float4 fB = *(const float4*)&smF[ob + 4];
                float4 vA = *(const float4*)&smVa[ob];
                float4 vB = *(const float4*)&smVa[ob + 4];
                acc = fmaf(vA.x, __builtin_amdgcn_rcpf(fmaf(lo_bf(ev.x), fA.x, 1.f)), acc);
                acc = fmaf(vA.y, __builtin_amdgcn_rcpf(fmaf(hi_bf(ev.x), fA.y, 1.f)), acc);
                acc = fmaf(vA.z, __builtin_amdgcn_rcpf(fmaf(lo_bf(ev.y), fA.z, 1.f)), acc);
                acc = fmaf(vA.w, __builtin_amdgcn_rcpf(fmaf(hi_bf(ev.y), fA.w, 1.f)), acc);
                acc = fmaf(vB.x, __builtin_amdgcn_rcpf(fmaf(lo_bf(ev.z), fB.x, 1.f)), acc);
                acc = fmaf(vB.y, __builtin_amdgcn_rcpf(fmaf(hi_bf(ev.z), fB.y, 1.f)), acc);
                acc = fmaf(vB.z, __builtin_amdgcn_rcpf(fmaf(lo_bf(ev.w), fB.z, 1.f)), acc);
                acc = fmaf(vB.w, __builtin_amdgcn_rcpf(fmaf(hi_bf(ev.w), fB.w, 1.f)), acc);
            }
            acc += __shfl_xor(acc, 1, 64);
            acc += __shfl_xor(acc, 2, 64);
            if (oq == 0) smS[tl] = sumVa - 2.f * acc + smBa3[tl];
        }
        __syncthreads();   // S3
        // ---- local softmax stats over 128 scores ----
        float m_g = 0.f, S_g = 0.f;
        if (tid < 128) {
            float s = smS[tid];
            float mm = s;
#pragma unroll
            for (int off = 32; off; off >>= 1) mm = fmaxf(mm, __shfl_xor(mm, off, 64));
            if (lane == 0) smT[w] = mm;
        }
        __syncthreads();   // S4
        if (tid < 128) {
            m_g = fmaxf(smT[0], smT[1]);
            float e = __expf(smS[tid] - m_g);
            smEe[tid] = e;
            float ls = e;
#pragma unroll
            for (int off = 32; off; off >>= 1) ls += __shfl_xor(ls, off, 64);
            if (lane == 0) smT[2 + w] = ls;
        }
        __syncthreads();   // S5
        m_g = fmaxf(smT[0], smT[1]);
        S_g = smT[2] + smT[3];
        // early publish: m,S travel while we stage P (drained by S7's vmcnt0)
        if (tid == 0) {
            coh_st(&bufP[256], __float_as_uint(m_g));
            coh_st(&bufP[257], __float_as_uint(S_g));
        }

        // ---- P_g partial: e-weighted IC rows of own slice ----
        {
            int rg = tid >> 6, oc = tid & 63, o4 = oc << 2;
            const u16* icp = ICb + (((size_t)t0) << 8) + o4;
            float4 a4 = {0.f, 0.f, 0.f, 0.f};
#pragma unroll 4
            for (int r = 0; r < 16; r++) {
                int row = (rg << 4) + r;
                float e = smEe[row];
                uint2 iv = *(const uint2*)(icp + ((size_t)row << 8));
                a4.x = fmaf(e, lo_bf(iv.x), a4.x);
                a4.y = fmaf(e, hi_bf(iv.x), a4.y);
                a4.z = fmaf(e, lo_bf(iv.y), a4.z);
                a4.w = fmaf(e, hi_bf(iv.y), a4.w);
            }
            *(float4*)&smScratch[rg * 256 + o4] = a4;
        }
        __syncthreads();   // S6
        // ---- publish P (own 256 f32 words) ----
        if (tid < 256) {
            float Pmine = 0.f;
#pragma unroll
            for (int rg = 0; rg < 8; rg++) Pmine += smScratch[rg * 256 + tid];
            coh_st(&bufP[tid], __float_as_uint(Pmine));
        }
        __syncthreads();   // S7 — vmcnt(0) drain = release fence for publishes
        // ---- flag store + poll 7 foreign flags ----
        if (tid == 0) coh_st(&flags[g], (uint32)t);
        if (tid < 8 && tid != g) {
            while (bud > 0) {
                if (atomicAdd(&flags[tid], 0u) == (uint32)t) break;
                bud--;
            }
        }
        __syncthreads();   // S8 — all 8 groups' data globally visible
        // ---- ONE batch of coherent loads: 8 P words/thread + 16 mS ----
        float p8[8];
        {
            const uint32* pb = &g_Pf[t & 1][b][0][0];
            if (tid < 256) {
#pragma unroll
                for (int g2 = 0; g2 < 8; g2++)
                    p8[g2] = __uint_as_float(coh_ld(&pb[g2 * 264 + tid]));
            } else if (tid < 256 + 16) {
                int i = tid & 15;        // g2 = i>>1, m/S = i&1
                smT[i] = __uint_as_float(coh_ld(&pb[(i >> 1) * 264 + 256 + (i & 1)]));
            }
        }
        __syncthreads();   // S8b — mS staged in LDS
        // ---- merge + full pred rebuild (tid<256) ----
        if (tid < 256) {
            float M = smT[0];
#pragma unroll
            for (int g2 = 1; g2 < 8; g2++) M = fmaxf(M, smT[2 * g2]);
            float L = 0.f, Pt = 0.f;
#pragma unroll
            for (int g2 = 0; g2 < 8; g2++) {
                float eg = __expf(smT[2 * g2] - M);
                L = fmaf(eg, smT[2 * g2 + 1], L);
                Pt = fmaf(eg, p8[g2], Pt);
            }
            float pr = p_val + uoh + Pt * __builtin_amdgcn_rcpf(L);
            if ((tid >> 5) == g) outb[((size_t)t << 8) + tid] = pr;
            smPred[tid] = pr;
            smQ[tid] = tanh_fast(pr);
        }
        __syncthreads();   // S9
    }
}

// ---------------- fallback (ws too small): diagnostic zero-fill ----------------
__global__ void zero_k(uint32* out, int n) {
    int i = blockIdx.x * 1024 + threadIdx.x;
    if (i < n) out[i] = 0;
}

extern "C" void kernel_launch(void* const* d_in, const int* in_sizes, int n_in,
                              void* d_out, int out_size, void* d_ws, size_t ws_size,
                              hipStream_t stream) {
    const float* in = (const float*)d_in[0];
    const float* Wa = (const float*)d_in[1];
    const float* Ua = (const float*)d_in[2];
    const float* Va = (const float*)d_in[3];
    const float* Ba1 = (const float*)d_in[4];
    const float* Ba2 = (const float*)d_in[5];
    const float* Ba3 = (const float*)d_in[6];
    const float* Wo = (const float*)d_in[7];
    const float* Uo = (const float*)d_in[8];
    const float* Co = (const float*)d_in[9];
    const float* Bo2 = (const float*)d_in[10];
    const float* Bo3 = (const float*)d_in[11];
    const float* Bo4 = (const float*)d_in[12];
    const float* emb = (const float*)d_in[13];
    float* out = (float*)d_out;
    char* ws = (char*)d_ws;

    if (ws_size < WS_NEEDED) {
        zero_k<<<(out_size + 1023) / 1024, 1024, 0, stream>>>((uint32*)out, out_size);
        return;
    }

    u16* E = (u16*)(ws + OFF_E);
    u16* icp = (u16*)(ws + OFF_IC);

    init_flags<<<1, 512, 0, stream>>>();
    setup_embWo<<<1, 256, 0, stream>>>(emb, Wo);
    gemm_pre<<<dim3(256, 6), 256, 0, stream>>>(in, Ua, Uo, Co, Ba2, Bo2, Bo3, Bo4, E, out, icp);
    seq8<<<256, NTH, 0, stream>>>(Wa, Va, Ba1, Ba3, E, icp, out);
}